// Round 1
// 885.495 us; speedup vs baseline: 1.3590x; 1.3590x over previous
//
#include <hip/hip_runtime.h>
#include <math.h>

#define B_  2
#define S_  2048
#define E_  1024
#define H_  16
#define D_  64
#define BS_ (B_*S_)   // 4096 rows
#define HD_ (H_*D_)   // 1024
#define LN_EPS 1e-5f

typedef __bf16 bf16x8 __attribute__((ext_vector_type(8)));
typedef float  f32x4  __attribute__((ext_vector_type(4)));

__device__ __forceinline__ unsigned short f2bf(float x) {
  union { float f; unsigned int u; } v; v.f = x;
  unsigned int r = (v.u + 0x7FFFu + ((v.u >> 16) & 1u)) >> 16;  // RNE
  return (unsigned short)r;
}

// fp32 -> bf16 hi (truncate) + bf16 lo (truncate of exact residual).
// Combined representation error <= 2^-16 relative: fp32-class for this op.
__device__ __forceinline__ void splitbf(float f, unsigned short &h, unsigned short &l) {
  unsigned int u = __float_as_uint(f);
  h = (unsigned short)(u >> 16);
  float hf = __uint_as_float(u & 0xFFFF0000u);
  l = (unsigned short)(__float_as_uint(f - hf) >> 16);
}

// ---------------------------------------------------------------------------
// MFMA GEMM: C = A[M,K] @ W[K,N] + bias.
// 128x128 tile, BK=32, 256 threads = 4 waves (2x2), 64x64 per wave,
// 4x4 fragments of mfma_f32_16x16x32_bf16, fp32 accumulate.
// SPLIT=1: bf16x3 error-compensated (hi*hi + hi*lo + lo*hi)  ~fp32 fidelity.
// SPLIT=0: plain bf16 (inputs RNE-rounded).
// MODE 0: fp32 C[M,N].
// MODE 1: bf16 out, head-major [b,h,s,d], value scaled by `scale`.
// MODE 2: bf16 out, transposed head-major [b,h,d,s]  (for V).
// A-frag layout: A[m=lane&15][k=quad*8+j]; B-frag: B[n=lane&15][k] (LDS holds
// B transposed). C/D: col=lane&15, row=quad*4+reg (verified m89).
// LDS rows padded to 40 bf16 (80 B): frag reads <=2-way bank alias (free),
// ushort4 writes 8B-aligned.
// ---------------------------------------------------------------------------
template<int MODE, int SPLIT>
__global__ __launch_bounds__(256) void gemm_mfma_k(
    const float* __restrict__ A, const float* __restrict__ W,
    const float* __restrict__ bias, float* __restrict__ Cf,
    unsigned short* __restrict__ Cb, int M, int N, int K, float scale)
{
  __shared__ unsigned short Ah[128][40];
  __shared__ unsigned short Bh[128][40];
  __shared__ unsigned short Al[SPLIT ? 128 : 1][SPLIT ? 40 : 2];
  __shared__ unsigned short Bl[SPLIT ? 128 : 1][SPLIT ? 40 : 2];

  const int t    = threadIdx.x;
  const int w    = t >> 6;
  const int lane = t & 63;
  const int quad = lane >> 4;
  const int l16  = lane & 15;
  const int wm   = (w >> 1) << 6;      // wave row offset within tile
  const int wn   = (w & 1) << 6;       // wave col offset within tile
  const int m0   = blockIdx.y << 7;
  const int n0   = blockIdx.x << 7;

  const int arow = t >> 3;             // A stage: row (unit i adds +32)
  const int acol = (t & 7) << 2;       // A stage: k offset (4 f32)
  const int bk   = (t & 7) << 2;       // B stage: k base (4 rows of W)
  const int bn   = (t >> 3) << 2;      // B stage: n base (4 cols)

  f32x4 acc[4][4];
#pragma unroll
  for (int i = 0; i < 4; ++i)
#pragma unroll
    for (int j = 0; j < 4; ++j) acc[i][j] = (f32x4){0.f, 0.f, 0.f, 0.f};

  float4 aV[4], bV[4];
  // prologue loads, k0 = 0
#pragma unroll
  for (int i = 0; i < 4; ++i)
    aV[i] = *(const float4*)&A[(size_t)(m0 + arow + i * 32) * K + acol];
#pragma unroll
  for (int r = 0; r < 4; ++r)
    bV[r] = *(const float4*)&W[(size_t)(bk + r) * N + n0 + bn];

  for (int k0 = 0; k0 < K; k0 += 32) {
    // ---- stage regs -> bf16 plane(s) in LDS ----
#pragma unroll
    for (int i = 0; i < 4; ++i) {
      const float* ap = (const float*)&aV[i];
      ushort4 h, l;
      if constexpr (SPLIT) {
        splitbf(ap[0], h.x, l.x); splitbf(ap[1], h.y, l.y);
        splitbf(ap[2], h.z, l.z); splitbf(ap[3], h.w, l.w);
      } else {
        h.x = f2bf(ap[0]); h.y = f2bf(ap[1]);
        h.z = f2bf(ap[2]); h.w = f2bf(ap[3]);
      }
      *(ushort4*)&Ah[arow + i * 32][acol] = h;
      if constexpr (SPLIT) *(ushort4*)&Al[arow + i * 32][acol] = l;
    }
    {
      const float* bp = (const float*)bV;   // bp[r*4+c]
#pragma unroll
      for (int j = 0; j < 4; ++j) {         // transpose 4x4 block
        ushort4 h, l;
        if constexpr (SPLIT) {
          splitbf(bp[0 * 4 + j], h.x, l.x); splitbf(bp[1 * 4 + j], h.y, l.y);
          splitbf(bp[2 * 4 + j], h.z, l.z); splitbf(bp[3 * 4 + j], h.w, l.w);
        } else {
          h.x = f2bf(bp[0 * 4 + j]); h.y = f2bf(bp[1 * 4 + j]);
          h.z = f2bf(bp[2 * 4 + j]); h.w = f2bf(bp[3 * 4 + j]);
        }
        *(ushort4*)&Bh[bn + j][bk] = h;
        if constexpr (SPLIT) *(ushort4*)&Bl[bn + j][bk] = l;
      }
    }
    __syncthreads();

    // issue next-tile global loads; latency hides under frag reads + MFMA
    if (k0 + 32 < K) {
#pragma unroll
      for (int i = 0; i < 4; ++i)
        aV[i] = *(const float4*)&A[(size_t)(m0 + arow + i * 32) * K + k0 + 32 + acol];
#pragma unroll
      for (int r = 0; r < 4; ++r)
        bV[r] = *(const float4*)&W[(size_t)(k0 + 32 + bk + r) * N + n0 + bn];
    }

    // ---- fragments + MFMA ----
    bf16x8 ah[4], bh[4], al[4], bl[4];
#pragma unroll
    for (int i = 0; i < 4; ++i) {
      ah[i] = *(const bf16x8*)&Ah[wm + i * 16 + l16][quad << 3];
      if constexpr (SPLIT) al[i] = *(const bf16x8*)&Al[wm + i * 16 + l16][quad << 3];
    }
#pragma unroll
    for (int j = 0; j < 4; ++j) {
      bh[j] = *(const bf16x8*)&Bh[wn + j * 16 + l16][quad << 3];
      if constexpr (SPLIT) bl[j] = *(const bf16x8*)&Bl[wn + j * 16 + l16][quad << 3];
    }
#pragma unroll
    for (int i = 0; i < 4; ++i)
#pragma unroll
      for (int j = 0; j < 4; ++j) {
        acc[i][j] = __builtin_amdgcn_mfma_f32_16x16x32_bf16(ah[i], bh[j], acc[i][j], 0, 0, 0);
        if constexpr (SPLIT) {
          acc[i][j] = __builtin_amdgcn_mfma_f32_16x16x32_bf16(ah[i], bl[j], acc[i][j], 0, 0, 0);
          acc[i][j] = __builtin_amdgcn_mfma_f32_16x16x32_bf16(al[i], bh[j], acc[i][j], 0, 0, 0);
        }
      }
    __syncthreads();
  }

  // ---- epilogue ----
#pragma unroll
  for (int j = 0; j < 4; ++j) {
    const int col = n0 + wn + j * 16 + l16;
    const float bb = bias[col];
#pragma unroll
    for (int i = 0; i < 4; ++i) {
      if constexpr (MODE == 0) {
#pragma unroll
        for (int r = 0; r < 4; ++r) {
          int row = m0 + wm + i * 16 + quad * 4 + r;
          Cf[(size_t)row * N + col] = acc[i][j][r] + bb;
        }
      } else if constexpr (MODE == 1) {
        const int h = col >> 6, d = col & 63;
#pragma unroll
        for (int r = 0; r < 4; ++r) {
          int row = m0 + wm + i * 16 + quad * 4 + r;
          int b = row >> 11, s = row & (S_ - 1);
          Cb[(((size_t)(b * H_ + h)) * S_ + s) * 64 + d] =
              f2bf((acc[i][j][r] + bb) * scale);
        }
      } else {
        const int h = col >> 6, d = col & 63;
        int row0 = m0 + wm + i * 16 + quad * 4;
        int b = row0 >> 11, s0 = row0 & (S_ - 1);
        ushort4 o;
        o.x = f2bf(acc[i][j][0] + bb); o.y = f2bf(acc[i][j][1] + bb);
        o.z = f2bf(acc[i][j][2] + bb); o.w = f2bf(acc[i][j][3] + bb);
        *(ushort4*)&Cb[((size_t)(b * H_ + h) * 64 + d) * S_ + s0] = o;
      }
    }
  }
}

// ---------------------------------------------------------------------------
// MFMA flash-style attention. grid (S/64, B*H), 256 threads = 4 waves.
// Each block: 64 q-rows; each wave: 16 q-rows. K-chunks of 64.
// Pass 1: QK^T (mfma 16x16x32 bf16) + online (m,l).  Pass 2: recompute,
// write normalized attn (fp32), P->LDS (bf16, per-wave tile), PV mfma.
// qt/kt: [bh][s][d] bf16 (q pre-scaled by 1/8).  vt: [bh][d][s] bf16.
// C-layout (verified m89): col = lane&15, row = (lane>>4)*4 + reg.
// A-layout: A[m=lane&15][k=quad*8+j];  B[k=quad*8+j][n=lane&15].
// ---------------------------------------------------------------------------
__global__ __launch_bounds__(256, 4) void attn_mfma(
    const unsigned short* __restrict__ qt, const unsigned short* __restrict__ kt,
    const unsigned short* __restrict__ vt, float* __restrict__ attn,
    float* __restrict__ ctx, const int* __restrict__ pmask)
{
  __shared__ unsigned short Qs[64][72];     // [q][d]    pad: rows 2-way only
  __shared__ unsigned short Ks[64][72];     // [k][d]
  __shared__ unsigned short Vs[64][72];     // [d][k]  (transposed tile)
  __shared__ unsigned short Ps[4][16][72];  // per-wave P tile [q][k]

  const int t    = threadIdx.x;
  const int w    = t >> 6;
  const int lane = t & 63;
  const int quad = lane >> 4;
  const int l16  = lane & 15;

  const int qblk = gridDim.x - 1 - blockIdx.x;   // heavy (causal) blocks first
  const int q0   = qblk * 64;
  const int bh   = blockIdx.y;
  const int isM  = pmask[0];
  const int kend = isM ? (q0 + 64) : S_;

  const unsigned short* qb = qt + (size_t)(bh * S_ + q0) * 64;
  const unsigned short* kb = kt + (size_t)bh * S_ * 64;
  const unsigned short* vb = vt + (size_t)bh * 64 * S_;

  // ---- stage Q tile (once) ----
#pragma unroll
  for (int i = 0; i < 2; ++i) {
    int idx = t + i * 256;
    int r = idx >> 3, c = (idx & 7) << 3;
    *(uint4*)&Qs[r][c] = *(const uint4*)&qb[(size_t)r * 64 + c];
  }
  __syncthreads();
  const bf16x8 qa0 = *(const bf16x8*)&Qs[w * 16 + l16][quad * 8];
  const bf16x8 qa1 = *(const bf16x8*)&Qs[w * 16 + l16][32 + quad * 8];

  float mrow[4] = {-1e30f, -1e30f, -1e30f, -1e30f};
  float lrow[4] = {0.f, 0.f, 0.f, 0.f};

  // ---------------- pass 1: stats ----------------
  for (int kc = 0; kc < kend; kc += 64) {
    __syncthreads();
#pragma unroll
    for (int i = 0; i < 2; ++i) {
      int idx = t + i * 256;
      int r = idx >> 3, c = (idx & 7) << 3;
      *(uint4*)&Ks[r][c] = *(const uint4*)&kb[(size_t)(kc + r) * 64 + c];
    }
    __syncthreads();

    f32x4 s[4];
#pragma unroll
    for (int j = 0; j < 4; ++j) {
      bf16x8 b0 = *(const bf16x8*)&Ks[j * 16 + l16][quad * 8];
      bf16x8 b1 = *(const bf16x8*)&Ks[j * 16 + l16][32 + quad * 8];
      f32x4 c0 = {0.f, 0.f, 0.f, 0.f};
      c0 = __builtin_amdgcn_mfma_f32_16x16x32_bf16(qa0, b0, c0, 0, 0, 0);
      c0 = __builtin_amdgcn_mfma_f32_16x16x32_bf16(qa1, b1, c0, 0, 0, 0);
      s[j] = c0;
    }
    if (isM && kc + 64 > q0) {
#pragma unroll
      for (int j = 0; j < 4; ++j) {
        int col = kc + j * 16 + l16;
#pragma unroll
        for (int r = 0; r < 4; ++r)
          if (col > q0 + w * 16 + quad * 4 + r) s[j][r] = -1e30f;
      }
    }
#pragma unroll
    for (int r = 0; r < 4; ++r) {
      float cm = fmaxf(fmaxf(s[0][r], s[1][r]), fmaxf(s[2][r], s[3][r]));
      cm = fmaxf(cm, __shfl_xor(cm, 1, 16));
      cm = fmaxf(cm, __shfl_xor(cm, 2, 16));
      cm = fmaxf(cm, __shfl_xor(cm, 4, 16));
      cm = fmaxf(cm, __shfl_xor(cm, 8, 16));
      float mn = fmaxf(mrow[r], cm);
      float cs = __expf(s[0][r] - mn) + __expf(s[1][r] - mn) +
                 __expf(s[2][r] - mn) + __expf(s[3][r] - mn);
      cs += __shfl_xor(cs, 1, 16);
      cs += __shfl_xor(cs, 2, 16);
      cs += __shfl_xor(cs, 4, 16);
      cs += __shfl_xor(cs, 8, 16);
      lrow[r] = lrow[r] * __expf(mrow[r] - mn) + cs;
      mrow[r] = mn;
    }
  }

  float invl[4];
#pragma unroll
  for (int r = 0; r < 4; ++r) invl[r] = 1.f / lrow[r];

  // ---------------- pass 2: attn write + PV ----------------
  f32x4 oacc[4];
#pragma unroll
  for (int n = 0; n < 4; ++n) oacc[n] = (f32x4){0.f, 0.f, 0.f, 0.f};

  for (int kc = 0; kc < kend; kc += 64) {
    __syncthreads();
#pragma unroll
    for (int i = 0; i < 2; ++i) {
      int idx = t + i * 256;
      int r = idx >> 3, c = (idx & 7) << 3;
      *(uint4*)&Ks[r][c] = *(const uint4*)&kb[(size_t)(kc + r) * 64 + c];
      *(uint4*)&Vs[r][c] = *(const uint4*)&vb[(size_t)r * S_ + kc + c];
    }
    __syncthreads();

    f32x4 s[4];
#pragma unroll
    for (int j = 0; j < 4; ++j) {
      bf16x8 b0 = *(const bf16x8*)&Ks[j * 16 + l16][quad * 8];
      bf16x8 b1 = *(const bf16x8*)&Ks[j * 16 + l16][32 + quad * 8];
      f32x4 c0 = {0.f, 0.f, 0.f, 0.f};
      c0 = __builtin_amdgcn_mfma_f32_16x16x32_bf16(qa0, b0, c0, 0, 0, 0);
      c0 = __builtin_amdgcn_mfma_f32_16x16x32_bf16(qa1, b1, c0, 0, 0, 0);
      s[j] = c0;
    }
    if (isM && kc + 64 > q0) {
#pragma unroll
      for (int j = 0; j < 4; ++j) {
        int col = kc + j * 16 + l16;
#pragma unroll
        for (int r = 0; r < 4; ++r)
          if (col > q0 + w * 16 + quad * 4 + r) s[j][r] = -1e30f;
      }
    }

    // p = exp(s - m) / l ; write attn + per-wave LDS P tile
#pragma unroll
    for (int j = 0; j < 4; ++j) {
#pragma unroll
      for (int r = 0; r < 4; ++r) {
        float p = __expf(s[j][r] - mrow[r]) * invl[r];
        attn[((size_t)bh * S_ + q0 + w * 16 + quad * 4 + r) * S_ + kc + j * 16 + l16] = p;
        Ps[w][quad * 4 + r][j * 16 + l16] = f2bf(p);
      }
    }
    // per-wave LDS dependency (write->read, same wave): lgkmcnt handles it

    bf16x8 pa0 = *(const bf16x8*)&Ps[w][l16][quad * 8];
    bf16x8 pa1 = *(const bf16x8*)&Ps[w][l16][32 + quad * 8];
#pragma unroll
    for (int n = 0; n < 4; ++n) {
      bf16x8 v0 = *(const bf16x8*)&Vs[n * 16 + l16][quad * 8];
      bf16x8 v1 = *(const bf16x8*)&Vs[n * 16 + l16][32 + quad * 8];
      oacc[n] = __builtin_amdgcn_mfma_f32_16x16x32_bf16(pa0, v0, oacc[n], 0, 0, 0);
      oacc[n] = __builtin_amdgcn_mfma_f32_16x16x32_bf16(pa1, v1, oacc[n], 0, 0, 0);
    }
  }

  // zero-fill fully-masked tail (d_out poisoned each launch)
  if (isM) {
    int row = q0 + (t >> 2);
    float4 z = {0.f, 0.f, 0.f, 0.f};
    for (int c = kend + ((t & 3) << 2); c < S_; c += 16)
      *(float4*)&attn[((size_t)bh * S_ + row) * S_ + c] = z;
  }

  // store O tile -> ctx[b*s][h*64+d]  (fp32)
  const int b = bh >> 4, h = bh & 15;
#pragma unroll
  for (int r = 0; r < 4; ++r) {
    int row = q0 + w * 16 + quad * 4 + r;
    size_t base = ((size_t)(b * S_ + row)) * HD_ + h * 64 + l16;
#pragma unroll
    for (int n = 0; n < 4; ++n)
      ctx[base + n * 16] = oacc[n][r];
  }
}

// ---------------------------------------------------------------------------
// In-place residual + LayerNorm over last dim (1024). One block per row.
// ---------------------------------------------------------------------------
__global__ __launch_bounds__(256) void ln_kernel(
    float* __restrict__ y, const float* __restrict__ resid)
{
  __shared__ float red[8];
  const int row = blockIdx.x, t = threadIdx.x;
  const size_t base = (size_t)row * 1024 + (t << 2);
  float4 x = *(float4*)&y[base];
  float4 r = *(const float4*)&resid[base];
  x.x += r.x; x.y += r.y; x.z += r.z; x.w += r.w;
  float sum = x.x + x.y + x.z + x.w;
  float ss  = x.x*x.x + x.y*x.y + x.z*x.z + x.w*x.w;
#pragma unroll
  for (int off = 1; off < 64; off <<= 1) {
    sum += __shfl_xor(sum, off);
    ss  += __shfl_xor(ss,  off);
  }
  const int wid = t >> 6;
  if ((t & 63) == 0) { red[wid] = sum; red[4 + wid] = ss; }
  __syncthreads();
  sum = red[0] + red[1] + red[2] + red[3];
  ss  = red[4] + red[5] + red[6] + red[7];
  const float mu  = sum * (1.f / 1024.f);
  const float var = ss * (1.f / 1024.f) - mu * mu;
  const float rs  = rsqrtf(var + LN_EPS);
  x.x = (x.x - mu) * rs; x.y = (x.y - mu) * rs;
  x.z = (x.z - mu) * rs; x.w = (x.w - mu) * rs;
  *(float4*)&y[base] = x;
}

// ---------------------------------------------------------------------------
extern "C" void kernel_launch(void* const* d_in, const int* in_sizes, int n_in,
                              void* d_out, int out_size, void* d_ws, size_t ws_size,
                              hipStream_t stream) {
  const float* q    = (const float*)d_in[0];
  const float* k    = (const float*)d_in[1];
  const float* v    = (const float*)d_in[2];
  const float* Wq   = (const float*)d_in[3];
  const float* bq   = (const float*)d_in[4];
  const float* Wk   = (const float*)d_in[5];
  const float* bk   = (const float*)d_in[6];
  const float* Wv   = (const float*)d_in[7];
  const float* bv   = (const float*)d_in[8];
  const float* Wo   = (const float*)d_in[9];
  const float* bo   = (const float*)d_in[10];
  const int*   mask = (const int*)d_in[11];

  float* outs = (float*)d_out;                         // [B*S, E]
  float* attn = outs + (size_t)BS_ * E_;               // [B, H, S, S]

  const size_t NBHSD = (size_t)BS_ * HD_;              // 4M elements
  unsigned short* qt = (unsigned short*)d_ws;          // bf16 [bh][s][d]
  unsigned short* kt = qt + NBHSD;
  unsigned short* vt = kt + NBHSD;                     // bf16 [bh][d][s]
  float* ctx = (float*)(vt + NBHSD);                   // fp32 [b*s][h*d]

  const dim3 gg(HD_ / 128, BS_ / 128);                 // (8, 32)
  // Q,K: bf16x3 split (score path, fp32-fidelity). V,O: plain bf16.
  gemm_mfma_k<1, 1><<<gg, 256, 0, stream>>>(q, Wq, bq, nullptr, qt, BS_, HD_, E_, 0.125f);
  gemm_mfma_k<1, 1><<<gg, 256, 0, stream>>>(k, Wk, bk, nullptr, kt, BS_, HD_, E_, 1.0f);
  gemm_mfma_k<2, 0><<<gg, 256, 0, stream>>>(v, Wv, bv, nullptr, vt, BS_, HD_, E_, 1.0f);

  attn_mfma<<<dim3(S_ / 64, B_ * H_), 256, 0, stream>>>(qt, kt, vt, attn, ctx, mask);

  gemm_mfma_k<0, 0><<<dim3(E_ / 128, BS_ / 128), 256, 0, stream>>>(ctx, Wo, bo, outs, nullptr, BS_, E_, HD_, 1.0f);
  ln_kernel<<<BS_, 256, 0, stream>>>(outs, q);
}